// Round 9
// baseline (40.856 us; speedup 1.0000x reference)
//
#include <hip/hip_runtime.h>
#include <hip/hip_bf16.h>
#include <stdint.h>

#define BATCH 1024
#define IN_DIM 784
#define NHEADS 10
#define NCOL 640          // 10 heads * 64 out
#define NB 9              // 8 basis + silu
#define KRED (IN_DIM*NB)  // 7056
#define KPAD 7168         // padded to multiple of 64
#define SK 16
#define KCHUNK (KPAD/SK)  // 448
#define BK 64
#define KITERS (KCHUNK/BK) // 7
#define BM 128
#define BN 128
#define ABUF (BM*BK)      // 8192 ushorts per A buffer (16 KB)
#define BBUF (BN*BK)      // 8192 ushorts per B buffer (16 KB)

typedef __bf16 v8bf __attribute__((ext_vector_type(8)));
typedef float  v4f  __attribute__((ext_vector_type(4)));

static __device__ __forceinline__ unsigned short f2bf(float f) {
    __hip_bfloat16 h = __float2bfloat16(f);
    return __builtin_bit_cast(unsigned short, h);
}
static __device__ __forceinline__ float bf2f(unsigned short u) {
    return __builtin_bit_cast(float, (uint32_t)u << 16);
}

// ---- kernel 1 (fused prep): blocks [0,1024) build A features; [1024,1514) build Wt ----
__global__ __launch_bounds__(256) void prep_kernel(const float* __restrict__ x,
                                                   const float* __restrict__ coef,
                                                   const float* __restrict__ sb,
                                                   const float* __restrict__ ssp,
                                                   const float* __restrict__ lmd,
                                                   unsigned short* __restrict__ A,
                                                   unsigned short* __restrict__ Wt) {
    __shared__ unsigned short LS[64 * 144];     // 18432 B (feat path uses first 14336 B)
    const int t = threadIdx.x;
    if (blockIdx.x < BATCH) {
        const int b = blockIdx.x;
        if (t < 196) {                           // 196 float4 = 784 x-values
            float4 xv4 = ((const float4*)(x + (size_t)b * IN_DIM))[t];
#pragma unroll
            for (int j = 0; j < 4; ++j) {
                int i = t * 4 + j;
                float xv = j == 0 ? xv4.x : j == 1 ? xv4.y : j == 2 ? xv4.z : xv4.w;
                float s = xv * 5.0f;
                int m0 = (int)s; m0 = m0 < 0 ? 0 : (m0 > 4 ? 4 : m0);
                float tt = s - (float)m0;
                float omt = 1.0f - tt, t2 = tt * tt, t3 = t2 * tt;
                float c0 = omt * omt * omt * (1.0f / 6.0f);
                float c1 = (3.0f * t3 - 6.0f * t2 + 4.0f) * (1.0f / 6.0f);
                float c2 = (-3.0f * t3 + 3.0f * t2 + 3.0f * tt + 1.0f) * (1.0f / 6.0f);
                float c3 = t3 * (1.0f / 6.0f);
                float sil = xv / (1.0f + expf(-xv));
                unsigned short* f = LS + i * NB;
#pragma unroll
                for (int k = 0; k < 8; ++k) {
                    int d = k - m0;
                    float v = (d == 0) ? c0 : (d == 1) ? c1 : (d == 2) ? c2 : (d == 3) ? c3 : 0.0f;
                    f[k] = f2bf(v);
                }
                f[8] = f2bf(sil);
            }
        }
        if (t < KPAD - KRED) LS[KRED + t] = 0;   // K padding
        __syncthreads();
        uint4* dst = (uint4*)(A + (size_t)b * KPAD);
        const uint4* srcv = (const uint4*)LS;
#pragma unroll
        for (int j = 0; j < 4; ++j) {            // 7168 ushorts = 896 x 16B
            int idx = j * 256 + t;
            if (idx < 896) dst[idx] = srcv[idx];
        }
    } else {
        const int blk = blockIdx.x - BATCH;      // 0..489
        const int h = blk / 49, ic = blk % 49;
        const int o = t & 63, iq = t >> 6;
#pragma unroll
        for (int ip = 0; ip < 4; ++ip) {
            int il = iq * 4 + ip;                // 0..15
            int i = ic * 16 + il;
            int hi = h * IN_DIM + i;
            float lm  = lmd[hi];
            float spv = ssp[(size_t)hi * 64 + o] * lm;
            float bse = sb [(size_t)hi * 64 + o] * lm;
            const float* cp = coef + ((size_t)hi * 64 + o) * 8;   // 32B contiguous, lanes span o
            unsigned short* d = LS + o * 144 + il * 9;
#pragma unroll
            for (int k = 0; k < 8; ++k) d[k] = f2bf(cp[k] * spv);
            d[8] = f2bf(bse);
        }
        __syncthreads();
#pragma unroll
        for (int j = 0; j < 5; ++j) {            // 64 rows x 288B = 1152 x 16B
            int idx = j * 256 + t;
            if (idx < 1152) {
                int row = idx / 18, c = idx - row * 18;
                uint4 v = *(const uint4*)(LS + row * 144 + c * 8);
                *(uint4*)(Wt + (size_t)(h * 64 + row) * KPAD + ic * 144 + c * 8) = v;
            }
        }
        if (ic == 48) {                          // zero K-pad: 64 rows x 224B = 896 x 16B
            uint4 z = uint4{0, 0, 0, 0};
#pragma unroll
            for (int j = 0; j < 4; ++j) {
                int idx = j * 256 + t;
                if (idx < 896) {
                    int row = idx / 14, c = idx - row * 14;
                    *(uint4*)(Wt + (size_t)(h * 64 + row) * KPAD + KRED + c * 8) = z;
                }
            }
        }
    }
}

// ---- kernel 2: GEMM 1024x640x7168 bf16 MFMA, tile 128x128, 4 waves, split-K=16 ----
// Wave tile 64x64 (4x4 16x16x32 fragments): LDS bytes/FLOP HALVED vs 32x64 wave
// tiles (LDS-BW-bound regime: 96KB per 2.1 MFLOP per K-step). 8x5x16 = 640 blocks;
// XCD x (= p%8) owns split-K slices {x, x+8} -> ~3MB L2 working set. Ping-pong dbuf
// (64KB -> 2 blocks/CU); __syncthreads()'s vmcnt(0) drain is the dbuf sync.
__global__ __launch_bounds__(256) void gemm_kernel(const unsigned short* __restrict__ A,
                                                   const unsigned short* __restrict__ Wt,
                                                   unsigned short* __restrict__ P) {
    __shared__ unsigned short As[2 * ABUF];      // 32 KB
    __shared__ unsigned short Bs[2 * BBUF];      // 32 KB
    const int p = blockIdx.x;
    const int sk = p & 15;
    const int rem = p >> 4;                      // 0..39
    const int bn = rem >> 3;                     // 0..4
    const int bm = rem & 7;                      // 0..7
    const int tid = threadIdx.x;
    const int w = tid >> 6, l = tid & 63;

    v4f acc[4][4];
#pragma unroll
    for (int a = 0; a < 4; ++a)
#pragma unroll
        for (int b = 0; b < 4; ++b) acc[a][b] = v4f{0.f, 0.f, 0.f, 0.f};

    const int k0 = sk * KCHUNK;
    const int arow0 = (w >> 1) * 64 + (l & 15);  // wave grid 2x2, each 64x64
    const int brow0 = (w & 1) * 64 + (l & 15);
    const int kkb = (l >> 4) * 16;               // byte offset of lane's 16B within 128B row

#define STAGE(buf, kc)                                                                   \
    {                                                                                    \
        _Pragma("unroll")                                                                \
        for (int r = 0; r < 4; ++r) {            /* A: 128 rows x 128B = 1024 chunks */  \
            int L = r * 256 + tid;                                                       \
            int row = L >> 3, scc = ((L & 7) ^ (row & 7)) * 8;                           \
            __builtin_amdgcn_global_load_lds(                                            \
                (const __attribute__((address_space(1))) void*)(A +                      \
                    (size_t)(bm * BM + row) * KPAD + (kc) + scc),                        \
                (__attribute__((address_space(3))) void*)(As + (buf) * ABUF +            \
                    (r * 256 + w * 64) * 8), 16, 0, 0);                                  \
        }                                                                                \
        _Pragma("unroll")                                                                \
        for (int r = 0; r < 4; ++r) {            /* B: 128 rows x 128B = 1024 chunks */  \
            int L = r * 256 + tid;                                                       \
            int row = L >> 3, scc = ((L & 7) ^ (row & 7)) * 8;                           \
            __builtin_amdgcn_global_load_lds(                                            \
                (const __attribute__((address_space(1))) void*)(Wt +                     \
                    (size_t)(bn * BN + row) * KPAD + (kc) + scc),                        \
                (__attribute__((address_space(3))) void*)(Bs + (buf) * BBUF +            \
                    (r * 256 + w * 64) * 8), 16, 0, 0);                                  \
        }                                                                                \
    }

#define COMPUTE(buf)                                                                     \
    {                                                                                    \
        const char* Ab = (const char*)(As + (buf) * ABUF);                               \
        const char* Bb = (const char*)(Bs + (buf) * BBUF);                               \
        _Pragma("unroll")                                                                \
        for (int ks = 0; ks < 2; ++ks) {                                                 \
            v8bf af[4], bfr[4];                                                          \
            _Pragma("unroll")                                                            \
            for (int f = 0; f < 4; ++f) {                                                \
                int ar = arow0 + f * 16;                                                 \
                af[f] = *(const v8bf*)(Ab + ((ar * 128 + ks * 64 + kkb) ^ ((ar & 7) << 4))); \
                int br = brow0 + f * 16;                                                 \
                bfr[f] = *(const v8bf*)(Bb + ((br * 128 + ks * 64 + kkb) ^ ((br & 7) << 4))); \
            }                                                                            \
            _Pragma("unroll")                                                            \
            for (int fi = 0; fi < 4; ++fi)                                               \
                _Pragma("unroll")                                                        \
                for (int fj = 0; fj < 4; ++fj)                                           \
                    acc[fi][fj] = __builtin_amdgcn_mfma_f32_16x16x32_bf16(               \
                        af[fi], bfr[fj], acc[fi][fj], 0, 0, 0);                          \
        }                                                                                \
    }

    STAGE(0, k0);
    __syncthreads();
    int cur = 0;
#pragma unroll 1
    for (int kt = 0; kt < KITERS; ++kt) {        // 7 iterations (odd -> cur-flag loop)
        if (kt + 1 < KITERS) STAGE(cur ^ 1, k0 + (kt + 1) * BK);
        COMPUTE(cur);
        __syncthreads();
        cur ^= 1;
    }
#undef STAGE
#undef COMPUTE

    // C/D layout: col = lane&15, row = 4*(lane>>4)+r   [measured m89]
    const int rowb = bm * BM + (w >> 1) * 64 + 4 * (l >> 4);
    const int colb = bn * BN + (w & 1) * 64 + (l & 15);
#pragma unroll
    for (int fi = 0; fi < 4; ++fi)
#pragma unroll
        for (int fj = 0; fj < 4; ++fj)
#pragma unroll
            for (int r = 0; r < 4; ++r)
                P[((size_t)sk * BATCH + rowb + fi * 16 + r) * NCOL + colb + fj * 16] =
                    f2bf(acc[fi][fj][r]);
}

// ---- kernel 3: block per (16 batch rows x head). Vectorized P reads, LDS MLP ----
__global__ __launch_bounds__(256) void epi_kernel(const unsigned short* __restrict__ P,
                                                  const float* __restrict__ W1,
                                                  const float* __restrict__ b1,
                                                  const float* __restrict__ W2,
                                                  const float* __restrict__ b2,
                                                  float* __restrict__ out) {
    __shared__ float h1s[16][64];                // 4 KB
    __shared__ float W1s[64 * 32];               // 8 KB
    const int t = threadIdx.x;
    const int b0 = blockIdx.x * 16;              // grid.x = 64
    const int h = blockIdx.y;

    // load W1[h]: 2048 floats = 512 float4
    {
        const float4* src = (const float4*)(W1 + (size_t)h * 2048);
        float4* dst = (float4*)W1s;
        dst[t] = src[t];
        dst[256 + t] = src[256 + t];
    }
    // phase 1: thread (row = t>>4, oq = t&15) sums 4 o-values over 16 split-K slices
    {
        const int row = t >> 4, oq = t & 15;     // o = oq*4 .. +3
        float y0 = 0.f, y1 = 0.f, y2 = 0.f, y3 = 0.f;
        size_t base = (size_t)(b0 + row) * NCOL + h * 64 + oq * 4;
#pragma unroll
        for (int s = 0; s < SK; ++s) {
            uint2 v = *(const uint2*)(P + (size_t)s * BATCH * NCOL + base);
            y0 += bf2f((unsigned short)(v.x & 0xffff));
            y1 += bf2f((unsigned short)(v.x >> 16));
            y2 += bf2f((unsigned short)(v.y & 0xffff));
            y3 += bf2f((unsigned short)(v.y >> 16));
        }
        h1s[row][oq * 4 + 0] = tanhf(y0);
        h1s[row][oq * 4 + 1] = tanhf(y1);
        h1s[row][oq * 4 + 2] = tanhf(y2);
        h1s[row][oq * 4 + 3] = tanhf(y3);
    }
    __syncthreads();
    // phase 2: thread (d = t&31, rq = t>>5) handles rows rq, rq+8
    {
        const int d = t & 31, rq = t >> 5;
        const float w2v = W2[h * 32 + d];
        const float b1v = b1[h * 32 + d];
        const float b2v = b2[h];
#pragma unroll
        for (int pass = 0; pass < 2; ++pass) {
            int row = pass * 8 + rq;
            float a2 = 0.f;
#pragma unroll 8
            for (int o = 0; o < 64; ++o) a2 += h1s[row][o] * W1s[o * 32 + d];
            float h2 = tanhf(a2 + b1v);
            float pp = h2 * w2v;
#pragma unroll
            for (int off = 16; off; off >>= 1) pp += __shfl_xor(pp, off);
            if (d == 0) out[(b0 + row) * NHEADS + h] = pp + b2v;
        }
    }
}

extern "C" void kernel_launch(void* const* d_in, const int* in_sizes, int n_in,
                              void* d_out, int out_size, void* d_ws, size_t ws_size,
                              hipStream_t stream) {
    const float* x    = (const float*)d_in[0];
    const float* coef = (const float*)d_in[1];
    const float* sb   = (const float*)d_in[2];
    const float* ssp  = (const float*)d_in[3];
    const float* lmd  = (const float*)d_in[4];
    const float* W1   = (const float*)d_in[5];
    const float* b1   = (const float*)d_in[6];
    const float* W2   = (const float*)d_in[7];
    const float* b2   = (const float*)d_in[8];
    float* out = (float*)d_out;

    unsigned short* Af = (unsigned short*)d_ws;                  // 1024*7168*2 = 14.68 MB
    unsigned short* Wt = Af + (size_t)BATCH * KPAD;              // 640*7168*2  =  9.18 MB
    unsigned short* P  = Wt + (size_t)NCOL * KPAD;               // 16*1024*640*2 = 20.97 MB

    hipLaunchKernelGGL(prep_kernel, dim3(BATCH + 490), dim3(256), 0, stream,
                       x, coef, sb, ssp, lmd, Af, Wt);
    hipLaunchKernelGGL(gemm_kernel, dim3(640), dim3(256), 0, stream, Af, Wt, P);
    hipLaunchKernelGGL(epi_kernel, dim3(64, NHEADS), dim3(256), 0, stream,
                       P, W1, b1, W2, b2, out);
}

// Round 10
// 37.539 us; speedup vs baseline: 1.0884x; 1.0884x over previous
//
#include <hip/hip_runtime.h>
#include <hip/hip_bf16.h>
#include <stdint.h>

#define BATCH 1024
#define IN_DIM 784
#define NHEADS 10
#define NCOL 640          // 10 heads * 64 out
#define NB 9              // 8 basis + silu
#define KRED (IN_DIM*NB)  // 7056
#define KPAD 7168         // padded to multiple of 64
#define SK 16
#define KCHUNK (KPAD/SK)  // 448
#define BK 64
#define KITERS (KCHUNK/BK) // 7
#define BM 128
#define BN 64
#define ABUF (BM*BK)      // 8192 ushorts per A buffer
#define BBUF (BN*BK)      // 4096 ushorts per B buffer

typedef __bf16 v8bf __attribute__((ext_vector_type(8)));
typedef float  v4f  __attribute__((ext_vector_type(4)));

static __device__ __forceinline__ unsigned short f2bf(float f) {
    __hip_bfloat16 h = __float2bfloat16(f);
    return __builtin_bit_cast(unsigned short, h);
}
static __device__ __forceinline__ float bf2f(unsigned short u) {
    return __builtin_bit_cast(float, (uint32_t)u << 16);
}

// ---- kernel 1 (fused prep): blocks [0,1024) build A features; [1024,1514) build Wt ----
__global__ __launch_bounds__(256) void prep_kernel(const float* __restrict__ x,
                                                   const float* __restrict__ coef,
                                                   const float* __restrict__ sb,
                                                   const float* __restrict__ ssp,
                                                   const float* __restrict__ lmd,
                                                   unsigned short* __restrict__ A,
                                                   unsigned short* __restrict__ Wt) {
    __shared__ unsigned short LS[64 * 144];     // 18432 B (feat path uses first 14336 B)
    const int t = threadIdx.x;
    if (blockIdx.x < BATCH) {
        const int b = blockIdx.x;
        if (t < 196) {                           // 196 float4 = 784 x-values
            float4 xv4 = ((const float4*)(x + (size_t)b * IN_DIM))[t];
#pragma unroll
            for (int j = 0; j < 4; ++j) {
                int i = t * 4 + j;
                float xv = j == 0 ? xv4.x : j == 1 ? xv4.y : j == 2 ? xv4.z : xv4.w;
                float s = xv * 5.0f;
                int m0 = (int)s; m0 = m0 < 0 ? 0 : (m0 > 4 ? 4 : m0);
                float tt = s - (float)m0;
                float omt = 1.0f - tt, t2 = tt * tt, t3 = t2 * tt;
                float c0 = omt * omt * omt * (1.0f / 6.0f);
                float c1 = (3.0f * t3 - 6.0f * t2 + 4.0f) * (1.0f / 6.0f);
                float c2 = (-3.0f * t3 + 3.0f * t2 + 3.0f * tt + 1.0f) * (1.0f / 6.0f);
                float c3 = t3 * (1.0f / 6.0f);
                float sil = xv / (1.0f + expf(-xv));
                unsigned short* f = LS + i * NB;
#pragma unroll
                for (int k = 0; k < 8; ++k) {
                    int d = k - m0;
                    float v = (d == 0) ? c0 : (d == 1) ? c1 : (d == 2) ? c2 : (d == 3) ? c3 : 0.0f;
                    f[k] = f2bf(v);
                }
                f[8] = f2bf(sil);
            }
        }
        if (t < KPAD - KRED) LS[KRED + t] = 0;   // K padding
        __syncthreads();
        uint4* dst = (uint4*)(A + (size_t)b * KPAD);
        const uint4* srcv = (const uint4*)LS;
#pragma unroll
        for (int j = 0; j < 4; ++j) {            // 7168 ushorts = 896 x 16B
            int idx = j * 256 + t;
            if (idx < 896) dst[idx] = srcv[idx];
        }
    } else {
        const int blk = blockIdx.x - BATCH;      // 0..489
        const int h = blk / 49, ic = blk % 49;
        const int o = t & 63, iq = t >> 6;
#pragma unroll
        for (int ip = 0; ip < 4; ++ip) {
            int il = iq * 4 + ip;                // 0..15
            int i = ic * 16 + il;
            int hi = h * IN_DIM + i;
            float lm  = lmd[hi];
            float spv = ssp[(size_t)hi * 64 + o] * lm;
            float bse = sb [(size_t)hi * 64 + o] * lm;
            const float* cp = coef + ((size_t)hi * 64 + o) * 8;   // 32B contiguous, lanes span o
            unsigned short* d = LS + o * 144 + il * 9;
#pragma unroll
            for (int k = 0; k < 8; ++k) d[k] = f2bf(cp[k] * spv);
            d[8] = f2bf(bse);
        }
        __syncthreads();
#pragma unroll
        for (int j = 0; j < 5; ++j) {            // 64 rows x 288B = 1152 x 16B
            int idx = j * 256 + t;
            if (idx < 1152) {
                int row = idx / 18, c = idx - row * 18;
                uint4 v = *(const uint4*)(LS + row * 144 + c * 8);
                *(uint4*)(Wt + (size_t)(h * 64 + row) * KPAD + ic * 144 + c * 8) = v;
            }
        }
        if (ic == 48) {                          // zero K-pad: 64 rows x 224B = 896 x 16B
            uint4 z = uint4{0, 0, 0, 0};
#pragma unroll
            for (int j = 0; j < 4; ++j) {
                int idx = j * 256 + t;
                if (idx < 896) {
                    int row = idx / 14, c = idx - row * 14;
                    *(uint4*)(Wt + (size_t)(h * 64 + row) * KPAD + KRED + c * 8) = z;
                }
            }
        }
    }
}

// ---- kernel 2: GEMM 1024x640x7168 bf16 MFMA, tile 128x64, 4 waves, split-K=16 ----
// Round-8 structure (best known) with SK 8->16: grid 1280 blocks @ 48KB LDS ->
// 3 resident blocks/CU (12 waves/CU), 5 queued -> block-boundary pipelining hides
// the per-K-step barrier drain (round-4's occupancy lever, extended).
__global__ __launch_bounds__(256) void gemm_kernel(const unsigned short* __restrict__ A,
                                                   const unsigned short* __restrict__ Wt,
                                                   unsigned short* __restrict__ P) {
    __shared__ unsigned short As[2 * ABUF];      // 32 KB
    __shared__ unsigned short Bs[2 * BBUF];      // 16 KB
    const int p = blockIdx.x;
    const int sk = p & 15;                       // XCD (p&7) holds slices {x, x+8}
    const int rem = p >> 4;                      // 0..79
    const int bn = rem >> 3;                     // 0..9
    const int bm = rem & 7;                      // 0..7
    const int tid = threadIdx.x;
    const int w = tid >> 6, l = tid & 63;

    v4f acc[2][4];
#pragma unroll
    for (int a = 0; a < 2; ++a)
#pragma unroll
        for (int b = 0; b < 4; ++b) acc[a][b] = v4f{0.f, 0.f, 0.f, 0.f};

    const int k0 = sk * KCHUNK;
    const int arow0 = w * 32 + (l & 15);
    const int kkb = (l >> 4) * 16;               // byte offset of lane's 16B within 128B row

#define STAGE(buf, kc)                                                                   \
    {                                                                                    \
        _Pragma("unroll")                                                                \
        for (int r = 0; r < 4; ++r) {            /* A: 128 rows x 128B = 1024 chunks */  \
            int L = r * 256 + tid;                                                       \
            int row = L >> 3, scc = ((L & 7) ^ (row & 7)) * 8;                           \
            __builtin_amdgcn_global_load_lds(                                            \
                (const __attribute__((address_space(1))) void*)(A +                      \
                    (size_t)(bm * BM + row) * KPAD + (kc) + scc),                        \
                (__attribute__((address_space(3))) void*)(As + (buf) * ABUF +            \
                    (r * 256 + w * 64) * 8), 16, 0, 0);                                  \
        }                                                                                \
        _Pragma("unroll")                                                                \
        for (int r = 0; r < 2; ++r) {            /* B: 64 rows x 128B = 512 chunks */    \
            int L = r * 256 + tid;                                                       \
            int row = L >> 3, scc = ((L & 7) ^ (row & 7)) * 8;                           \
            __builtin_amdgcn_global_load_lds(                                            \
                (const __attribute__((address_space(1))) void*)(Wt +                     \
                    (size_t)(bn * BN + row) * KPAD + (kc) + scc),                        \
                (__attribute__((address_space(3))) void*)(Bs + (buf) * BBUF +            \
                    (r * 256 + w * 64) * 8), 16, 0, 0);                                  \
        }                                                                                \
    }

#define COMPUTE(buf)                                                                     \
    {                                                                                    \
        const char* Ab = (const char*)(As + (buf) * ABUF);                               \
        const char* Bb = (const char*)(Bs + (buf) * BBUF);                               \
        _Pragma("unroll")                                                                \
        for (int ks = 0; ks < 2; ++ks) {                                                 \
            v8bf af[2], bfr[4];                                                          \
            _Pragma("unroll")                                                            \
            for (int f = 0; f < 2; ++f) {                                                \
                int ar = arow0 + f * 16;                                                 \
                af[f] = *(const v8bf*)(Ab + ((ar * 128 + ks * 64 + kkb) ^ ((ar & 7) << 4))); \
            }                                                                            \
            _Pragma("unroll")                                                            \
            for (int g = 0; g < 4; ++g) {                                                \
                int br = g * 16 + (l & 15);                                              \
                bfr[g] = *(const v8bf*)(Bb + ((br * 128 + ks * 64 + kkb) ^ ((br & 7) << 4))); \
            }                                                                            \
            _Pragma("unroll")                                                            \
            for (int fi = 0; fi < 2; ++fi)                                               \
                _Pragma("unroll")                                                        \
                for (int fj = 0; fj < 4; ++fj)                                           \
                    acc[fi][fj] = __builtin_amdgcn_mfma_f32_16x16x32_bf16(               \
                        af[fi], bfr[fj], acc[fi][fj], 0, 0, 0);                          \
        }                                                                                \
    }

    STAGE(0, k0);
    __syncthreads();
    int cur = 0;
#pragma unroll 1
    for (int kt = 0; kt < KITERS; ++kt) {        // 7 iterations
        if (kt + 1 < KITERS) STAGE(cur ^ 1, k0 + (kt + 1) * BK);
        COMPUTE(cur);
        __syncthreads();
        cur ^= 1;
    }
#undef STAGE
#undef COMPUTE

    // C/D layout: col = lane&15, row = 4*(lane>>4)+r   [measured m89]
    const int rowb = bm * BM + w * 32 + 4 * (l >> 4);
    const int colb = bn * BN + (l & 15);
#pragma unroll
    for (int fi = 0; fi < 2; ++fi)
#pragma unroll
        for (int fj = 0; fj < 4; ++fj)
#pragma unroll
            for (int r = 0; r < 4; ++r)
                P[((size_t)sk * BATCH + rowb + fi * 16 + r) * NCOL + colb + fj * 16] =
                    f2bf(acc[fi][fj][r]);
}

// ---- kernel 3: block per (16 batch rows x head). Vectorized P reads, LDS MLP ----
__global__ __launch_bounds__(256) void epi_kernel(const unsigned short* __restrict__ P,
                                                  const float* __restrict__ W1,
                                                  const float* __restrict__ b1,
                                                  const float* __restrict__ W2,
                                                  const float* __restrict__ b2,
                                                  float* __restrict__ out) {
    __shared__ float h1s[16][64];                // 4 KB
    __shared__ float W1s[64 * 32];               // 8 KB
    const int t = threadIdx.x;
    const int b0 = blockIdx.x * 16;              // grid.x = 64
    const int h = blockIdx.y;

    // load W1[h]: 2048 floats = 512 float4
    {
        const float4* src = (const float4*)(W1 + (size_t)h * 2048);
        float4* dst = (float4*)W1s;
        dst[t] = src[t];
        dst[256 + t] = src[256 + t];
    }
    // phase 1: thread (row = t>>4, oq = t&15) sums 4 o-values over 16 split-K slices
    {
        const int row = t >> 4, oq = t & 15;     // o = oq*4 .. +3
        float y0 = 0.f, y1 = 0.f, y2 = 0.f, y3 = 0.f;
        size_t base = (size_t)(b0 + row) * NCOL + h * 64 + oq * 4;
#pragma unroll
        for (int s = 0; s < SK; ++s) {
            uint2 v = *(const uint2*)(P + (size_t)s * BATCH * NCOL + base);
            y0 += bf2f((unsigned short)(v.x & 0xffff));
            y1 += bf2f((unsigned short)(v.x >> 16));
            y2 += bf2f((unsigned short)(v.y & 0xffff));
            y3 += bf2f((unsigned short)(v.y >> 16));
        }
        h1s[row][oq * 4 + 0] = tanhf(y0);
        h1s[row][oq * 4 + 1] = tanhf(y1);
        h1s[row][oq * 4 + 2] = tanhf(y2);
        h1s[row][oq * 4 + 3] = tanhf(y3);
    }
    __syncthreads();
    // phase 2: thread (d = t&31, rq = t>>5) handles rows rq, rq+8
    {
        const int d = t & 31, rq = t >> 5;
        const float w2v = W2[h * 32 + d];
        const float b1v = b1[h * 32 + d];
        const float b2v = b2[h];
#pragma unroll
        for (int pass = 0; pass < 2; ++pass) {
            int row = pass * 8 + rq;
            float a2 = 0.f;
#pragma unroll 8
            for (int o = 0; o < 64; ++o) a2 += h1s[row][o] * W1s[o * 32 + d];
            float h2 = tanhf(a2 + b1v);
            float pp = h2 * w2v;
#pragma unroll
            for (int off = 16; off; off >>= 1) pp += __shfl_xor(pp, off);
            if (d == 0) out[(b0 + row) * NHEADS + h] = pp + b2v;
        }
    }
}

extern "C" void kernel_launch(void* const* d_in, const int* in_sizes, int n_in,
                              void* d_out, int out_size, void* d_ws, size_t ws_size,
                              hipStream_t stream) {
    const float* x    = (const float*)d_in[0];
    const float* coef = (const float*)d_in[1];
    const float* sb   = (const float*)d_in[2];
    const float* ssp  = (const float*)d_in[3];
    const float* lmd  = (const float*)d_in[4];
    const float* W1   = (const float*)d_in[5];
    const float* b1   = (const float*)d_in[6];
    const float* W2   = (const float*)d_in[7];
    const float* b2   = (const float*)d_in[8];
    float* out = (float*)d_out;

    unsigned short* Af = (unsigned short*)d_ws;                  // 1024*7168*2 = 14.68 MB
    unsigned short* Wt = Af + (size_t)BATCH * KPAD;              // 640*7168*2  =  9.18 MB
    unsigned short* P  = Wt + (size_t)NCOL * KPAD;               // 16*1024*640*2 = 20.97 MB

    hipLaunchKernelGGL(prep_kernel, dim3(BATCH + 490), dim3(256), 0, stream,
                       x, coef, sb, ssp, lmd, Af, Wt);
    hipLaunchKernelGGL(gemm_kernel, dim3(1280), dim3(256), 0, stream, Af, Wt, P);
    hipLaunchKernelGGL(epi_kernel, dim3(64, NHEADS), dim3(256), 0, stream,
                       P, W1, b1, W2, b2, out);
}

// Round 11
// 35.712 us; speedup vs baseline: 1.1440x; 1.0512x over previous
//
#include <hip/hip_runtime.h>
#include <hip/hip_bf16.h>
#include <stdint.h>

#define BATCH 1024
#define IN_DIM 784
#define NHEADS 10
#define NCOL 640          // 10 heads * 64 out
#define NB 9              // 8 basis + silu
#define KRED (IN_DIM*NB)  // 7056
#define KPAD 7168         // padded to multiple of 64
#define SK 8
#define KCHUNK (KPAD/SK)  // 896
#define BK 64
#define KITERS (KCHUNK/BK) // 14
#define BM 128
#define BN 64
#define ABUF (BM*BK)      // 8192 ushorts per A buffer
#define BBUF (BN*BK)      // 4096 ushorts per B buffer

typedef __bf16 v8bf __attribute__((ext_vector_type(8)));
typedef float  v4f  __attribute__((ext_vector_type(4)));

static __device__ __forceinline__ unsigned short f2bf(float f) {
    __hip_bfloat16 h = __float2bfloat16(f);
    return __builtin_bit_cast(unsigned short, h);
}
static __device__ __forceinline__ float bf2f(unsigned short u) {
    return __builtin_bit_cast(float, (uint32_t)u << 16);
}

// ---- kernel 1 (fused prep): blocks [0,1024) build A features; [1024,1514) build Wt ----
__global__ __launch_bounds__(256) void prep_kernel(const float* __restrict__ x,
                                                   const float* __restrict__ coef,
                                                   const float* __restrict__ sb,
                                                   const float* __restrict__ ssp,
                                                   const float* __restrict__ lmd,
                                                   unsigned short* __restrict__ A,
                                                   unsigned short* __restrict__ Wt) {
    __shared__ unsigned short LS[64 * 144];     // 18432 B (feat path uses first 14336 B)
    const int t = threadIdx.x;
    if (blockIdx.x < BATCH) {
        const int b = blockIdx.x;
        if (t < 196) {                           // 196 float4 = 784 x-values
            float4 xv4 = ((const float4*)(x + (size_t)b * IN_DIM))[t];
#pragma unroll
            for (int j = 0; j < 4; ++j) {
                int i = t * 4 + j;
                float xv = j == 0 ? xv4.x : j == 1 ? xv4.y : j == 2 ? xv4.z : xv4.w;
                float s = xv * 5.0f;
                int m0 = (int)s; m0 = m0 < 0 ? 0 : (m0 > 4 ? 4 : m0);
                float tt = s - (float)m0;
                float omt = 1.0f - tt, t2 = tt * tt, t3 = t2 * tt;
                float c0 = omt * omt * omt * (1.0f / 6.0f);
                float c1 = (3.0f * t3 - 6.0f * t2 + 4.0f) * (1.0f / 6.0f);
                float c2 = (-3.0f * t3 + 3.0f * t2 + 3.0f * tt + 1.0f) * (1.0f / 6.0f);
                float c3 = t3 * (1.0f / 6.0f);
                float sil = xv / (1.0f + expf(-xv));
                unsigned short* f = LS + i * NB;
#pragma unroll
                for (int k = 0; k < 8; ++k) {
                    int d = k - m0;
                    float v = (d == 0) ? c0 : (d == 1) ? c1 : (d == 2) ? c2 : (d == 3) ? c3 : 0.0f;
                    f[k] = f2bf(v);
                }
                f[8] = f2bf(sil);
            }
        }
        if (t < KPAD - KRED) LS[KRED + t] = 0;   // K padding
        __syncthreads();
        uint4* dst = (uint4*)(A + (size_t)b * KPAD);
        const uint4* srcv = (const uint4*)LS;
#pragma unroll
        for (int j = 0; j < 4; ++j) {            // 7168 ushorts = 896 x 16B
            int idx = j * 256 + t;
            if (idx < 896) dst[idx] = srcv[idx];
        }
    } else {
        const int blk = blockIdx.x - BATCH;      // 0..489
        const int h = blk / 49, ic = blk % 49;
        const int o = t & 63, iq = t >> 6;
#pragma unroll
        for (int ip = 0; ip < 4; ++ip) {
            int il = iq * 4 + ip;                // 0..15
            int i = ic * 16 + il;
            int hi = h * IN_DIM + i;
            float lm  = lmd[hi];
            float spv = ssp[(size_t)hi * 64 + o] * lm;
            float bse = sb [(size_t)hi * 64 + o] * lm;
            const float* cp = coef + ((size_t)hi * 64 + o) * 8;   // 32B contiguous, lanes span o
            unsigned short* d = LS + o * 144 + il * 9;
#pragma unroll
            for (int k = 0; k < 8; ++k) d[k] = f2bf(cp[k] * spv);
            d[8] = f2bf(bse);
        }
        __syncthreads();
#pragma unroll
        for (int j = 0; j < 5; ++j) {            // 64 rows x 288B = 1152 x 16B
            int idx = j * 256 + t;
            if (idx < 1152) {
                int row = idx / 18, c = idx - row * 18;
                uint4 v = *(const uint4*)(LS + row * 144 + c * 8);
                *(uint4*)(Wt + (size_t)(h * 64 + row) * KPAD + ic * 144 + c * 8) = v;
            }
        }
        if (ic == 48) {                          // zero K-pad: 64 rows x 224B = 896 x 16B
            uint4 z = uint4{0, 0, 0, 0};
#pragma unroll
            for (int j = 0; j < 4; ++j) {
                int idx = j * 256 + t;
                if (idx < 896) {
                    int row = idx / 14, c = idx - row * 14;
                    *(uint4*)(Wt + (size_t)(h * 64 + row) * KPAD + KRED + c * 8) = z;
                }
            }
        }
    }
}

// ---- kernel 2: GEMM 1024x640x7168 bf16 MFMA, tile 128x64, 4 waves, split-K=8 ----
// Round-8 structure (best measured: 36.3us total). C-write now FRAGMENT-NATIVE:
// each thread packs acc[fi][fj][0..3] (4 consecutive rows, 1 col) into a uint2 and
// stores 8 coalesced 8B words (512B/wave-instr) -- replaces 32 scalar 2B stores
// at 1280B stride. P layout: uint2 idx = (((((sk*8+bm)*10+bn)*4+w)*2+fi)*4+fj)*64+l,
// holding rows bm*128+w*32+fi*16+(l>>4)*4+r, col bn*64+fj*16+(l&15).
__global__ __launch_bounds__(256) void gemm_kernel(const unsigned short* __restrict__ A,
                                                   const unsigned short* __restrict__ Wt,
                                                   unsigned short* __restrict__ P) {
    __shared__ unsigned short As[2 * ABUF];      // 32 KB
    __shared__ unsigned short Bs[2 * BBUF];      // 16 KB
    const int p = blockIdx.x;
    const int sk = p & 7;                        // XCD x owns split-K slice x
    const int rem = p >> 3;
    const int bn = rem >> 3;                     // 0..9
    const int bm = rem & 7;                      // 0..7
    const int tid = threadIdx.x;
    const int w = tid >> 6, l = tid & 63;

    v4f acc[2][4];
#pragma unroll
    for (int a = 0; a < 2; ++a)
#pragma unroll
        for (int b = 0; b < 4; ++b) acc[a][b] = v4f{0.f, 0.f, 0.f, 0.f};

    const int k0 = sk * KCHUNK;
    const int arow0 = w * 32 + (l & 15);
    const int kkb = (l >> 4) * 16;               // byte offset of lane's 16B within 128B row

#define STAGE(buf, kc)                                                                   \
    {                                                                                    \
        _Pragma("unroll")                                                                \
        for (int r = 0; r < 4; ++r) {            /* A: 128 rows x 128B = 1024 chunks */  \
            int L = r * 256 + tid;                                                       \
            int row = L >> 3, scc = ((L & 7) ^ (row & 7)) * 8;                           \
            __builtin_amdgcn_global_load_lds(                                            \
                (const __attribute__((address_space(1))) void*)(A +                      \
                    (size_t)(bm * BM + row) * KPAD + (kc) + scc),                        \
                (__attribute__((address_space(3))) void*)(As + (buf) * ABUF +            \
                    (r * 256 + w * 64) * 8), 16, 0, 0);                                  \
        }                                                                                \
        _Pragma("unroll")                                                                \
        for (int r = 0; r < 2; ++r) {            /* B: 64 rows x 128B = 512 chunks */    \
            int L = r * 256 + tid;                                                       \
            int row = L >> 3, scc = ((L & 7) ^ (row & 7)) * 8;                           \
            __builtin_amdgcn_global_load_lds(                                            \
                (const __attribute__((address_space(1))) void*)(Wt +                     \
                    (size_t)(bn * BN + row) * KPAD + (kc) + scc),                        \
                (__attribute__((address_space(3))) void*)(Bs + (buf) * BBUF +            \
                    (r * 256 + w * 64) * 8), 16, 0, 0);                                  \
        }                                                                                \
    }

#define COMPUTE(buf)                                                                     \
    {                                                                                    \
        const char* Ab = (const char*)(As + (buf) * ABUF);                               \
        const char* Bb = (const char*)(Bs + (buf) * BBUF);                               \
        _Pragma("unroll")                                                                \
        for (int ks = 0; ks < 2; ++ks) {                                                 \
            v8bf af[2], bfr[4];                                                          \
            _Pragma("unroll")                                                            \
            for (int f = 0; f < 2; ++f) {                                                \
                int ar = arow0 + f * 16;                                                 \
                af[f] = *(const v8bf*)(Ab + ((ar * 128 + ks * 64 + kkb) ^ ((ar & 7) << 4))); \
            }                                                                            \
            _Pragma("unroll")                                                            \
            for (int g = 0; g < 4; ++g) {                                                \
                int br = g * 16 + (l & 15);                                              \
                bfr[g] = *(const v8bf*)(Bb + ((br * 128 + ks * 64 + kkb) ^ ((br & 7) << 4))); \
            }                                                                            \
            _Pragma("unroll")                                                            \
            for (int fi = 0; fi < 2; ++fi)                                               \
                _Pragma("unroll")                                                        \
                for (int fj = 0; fj < 4; ++fj)                                           \
                    acc[fi][fj] = __builtin_amdgcn_mfma_f32_16x16x32_bf16(               \
                        af[fi], bfr[fj], acc[fi][fj], 0, 0, 0);                          \
        }                                                                                \
    }

    STAGE(0, k0);
    __syncthreads();
#pragma unroll 1
    for (int t2 = 0; t2 < KITERS / 2; ++t2) {    // 7 double-iterations
        STAGE(1, k0 + (2 * t2 + 1) * BK);
        COMPUTE(0);
        __syncthreads();
        if (t2 + 1 < KITERS / 2) STAGE(0, k0 + (2 * t2 + 2) * BK);
        COMPUTE(1);
        __syncthreads();
    }
#undef STAGE
#undef COMPUTE

    // fragment-native packed C-write (coalesced 8B/lane)
    uint2* P2 = (uint2*)P;
    const int baseidx = (((sk * 8 + bm) * 10 + bn) * 4 + w) * 2;
#pragma unroll
    for (int fi = 0; fi < 2; ++fi)
#pragma unroll
        for (int fj = 0; fj < 4; ++fj) {
            uint2 v;
            v.x = (uint32_t)f2bf(acc[fi][fj][0]) | ((uint32_t)f2bf(acc[fi][fj][1]) << 16);
            v.y = (uint32_t)f2bf(acc[fi][fj][2]) | ((uint32_t)f2bf(acc[fi][fj][3]) << 16);
            P2[(size_t)(((baseidx + fi) * 4 + fj) * 64 + l)] = v;
        }
}

// ---- kernel 3: block per (16 batch rows x head); reads fragment-native P ----
__global__ __launch_bounds__(256) void epi_kernel(const unsigned short* __restrict__ P,
                                                  const float* __restrict__ W1,
                                                  const float* __restrict__ b1,
                                                  const float* __restrict__ W2,
                                                  const float* __restrict__ b2,
                                                  float* __restrict__ out) {
    __shared__ float h1s[16][65];                // padded (+1) vs bank conflicts
    __shared__ float W1s[64 * 32];               // 8 KB
    const int t = threadIdx.x;
    const int bx = blockIdx.x;                   // 0..63
    const int b0 = bx * 16;
    const int h = blockIdx.y;
    const int bm = bx >> 3;                      // row-tile
    const int sub = bx & 7;
    const int w = sub >> 1, fi = sub & 1;        // wave / fi half within tile

    // load W1[h]: 2048 floats = 512 float4
    {
        const float4* src = (const float4*)(W1 + (size_t)h * 2048);
        float4* dst = (float4*)W1s;
        dst[t] = src[t];
        dst[256 + t] = src[256 + t];
    }
    // phase 1: thread (fj = t>>6, l = t&63) owns col fj*16+(l&15), rows (l>>4)*4..+3
    {
        const int fj = t >> 6, l = t & 63;
        const int q = l >> 4, c15 = l & 15;
        const uint2* P2 = (const uint2*)P;
        float y0 = 0.f, y1 = 0.f, y2 = 0.f, y3 = 0.f;
#pragma unroll
        for (int s = 0; s < SK; ++s) {
            uint2 v = P2[(size_t)((((((s * 8 + bm) * 10 + h) * 4 + w) * 2 + fi) * 4 + fj) * 64 + l)];
            y0 += bf2f((unsigned short)(v.x & 0xffff));
            y1 += bf2f((unsigned short)(v.x >> 16));
            y2 += bf2f((unsigned short)(v.y & 0xffff));
            y3 += bf2f((unsigned short)(v.y >> 16));
        }
        const int col = fj * 16 + c15;
        h1s[q * 4 + 0][col] = tanhf(y0);
        h1s[q * 4 + 1][col] = tanhf(y1);
        h1s[q * 4 + 2][col] = tanhf(y2);
        h1s[q * 4 + 3][col] = tanhf(y3);
    }
    __syncthreads();
    // phase 2: thread (d = t&31, rq = t>>5) handles rows rq, rq+8
    {
        const int d = t & 31, rq = t >> 5;
        const float w2v = W2[h * 32 + d];
        const float b1v = b1[h * 32 + d];
        const float b2v = b2[h];
#pragma unroll
        for (int pass = 0; pass < 2; ++pass) {
            int row = pass * 8 + rq;
            float a2 = 0.f;
#pragma unroll 8
            for (int o = 0; o < 64; ++o) a2 += h1s[row][o] * W1s[o * 32 + d];
            float h2 = tanhf(a2 + b1v);
            float pp = h2 * w2v;
#pragma unroll
            for (int off = 16; off; off >>= 1) pp += __shfl_xor(pp, off);
            if (d == 0) out[(b0 + row) * NHEADS + h] = pp + b2v;
        }
    }
}

extern "C" void kernel_launch(void* const* d_in, const int* in_sizes, int n_in,
                              void* d_out, int out_size, void* d_ws, size_t ws_size,
                              hipStream_t stream) {
    const float* x    = (const float*)d_in[0];
    const float* coef = (const float*)d_in[1];
    const float* sb   = (const float*)d_in[2];
    const float* ssp  = (const float*)d_in[3];
    const float* lmd  = (const float*)d_in[4];
    const float* W1   = (const float*)d_in[5];
    const float* b1   = (const float*)d_in[6];
    const float* W2   = (const float*)d_in[7];
    const float* b2   = (const float*)d_in[8];
    float* out = (float*)d_out;

    unsigned short* Af = (unsigned short*)d_ws;                  // 1024*7168*2 = 14.68 MB
    unsigned short* Wt = Af + (size_t)BATCH * KPAD;              // 640*7168*2  =  9.18 MB
    unsigned short* P  = Wt + (size_t)NCOL * KPAD;               // 8*1024*640*2 = 10.49 MB

    hipLaunchKernelGGL(prep_kernel, dim3(BATCH + 490), dim3(256), 0, stream,
                       x, coef, sb, ssp, lmd, Af, Wt);
    hipLaunchKernelGGL(gemm_kernel, dim3(640), dim3(256), 0, stream, Af, Wt, P);
    hipLaunchKernelGGL(epi_kernel, dim3(64, NHEADS), dim3(256), 0, stream,
                       P, W1, b1, W2, b2, out);
}